// Round 1
// baseline (212.734 us; speedup 1.0000x reference)
//
#include <hip/hip_runtime.h>

#define SDIM 14
#define L_COORD 5.0f
#define L_NOOBJ 0.5f
#define BATCH 4096
#define CELLS (BATCH * SDIM * SDIM)   // 802816
#define BLOCK 256
#define NBLOCKS (CELLS / BLOCK)       // 3136

__global__ __launch_bounds__(BLOCK) void yolo_partial(
    const float* __restrict__ pred, const float* __restrict__ targ,
    float* __restrict__ partial) {
    const int cell = blockIdx.x * BLOCK + threadIdx.x;

    // 30 floats per cell, 120 B, 8-byte aligned -> 15 x float2 loads each
    const float2* p2 = reinterpret_cast<const float2*>(pred) + (size_t)cell * 15;
    const float2* t2 = reinterpret_cast<const float2*>(targ) + (size_t)cell * 15;
    float P[30], T[30];
#pragma unroll
    for (int j = 0; j < 15; ++j) {
        float2 v = p2[j]; P[2 * j] = v.x; P[2 * j + 1] = v.y;
        float2 w = t2[j]; T[2 * j] = w.x; T[2 * j + 1] = w.y;
    }

    float loss;
    if (T[4] > 0.0f) {
        // ---- class loss (channels 10..29) ----
        float cls = 0.0f;
#pragma unroll
        for (int c = 10; c < 30; ++c) { float d = P[c] - T[c]; cls += d * d; }

        // ---- IoU of both pred boxes vs target box 0 ----
        const float invS = 1.0f / (float)SDIM;
        const float t1x = T[0] * invS - T[2] * 0.5f;
        const float t1y = T[1] * invS - T[3] * 0.5f;
        const float t2x = T[0] * invS + T[2] * 0.5f;
        const float t2y = T[1] * invS + T[3] * 0.5f;
        const float area_t = (t2x - t1x) * (t2y - t1y);

        float iou0, iou1;
#pragma unroll
        for (int k = 0; k < 2; ++k) {   // k is compile-time after unroll
            const float bx = P[5 * k + 0], by = P[5 * k + 1];
            const float bw = P[5 * k + 2], bh = P[5 * k + 3];
            const float p1x = bx * invS - bw * 0.5f;
            const float p1y = by * invS - bh * 0.5f;
            const float p2x = bx * invS + bw * 0.5f;
            const float p2y = by * invS + bh * 0.5f;
            const float ltx = fmaxf(p1x, t1x), lty = fmaxf(p1y, t1y);
            const float rbx = fminf(p2x, t2x), rby = fminf(p2y, t2y);
            const float wx = fmaxf(rbx - ltx, 0.0f);
            const float wy = fmaxf(rby - lty, 0.0f);
            const float inter = wx * wy;
            const float area_p = (p2x - p1x) * (p2y - p1y);
            const float v = inter / (area_p + area_t - inter);
            if (k == 0) iou0 = v; else iou1 = v;
        }

        const bool pick1 = (iou0 <= iou1);
        const float iou_best = pick1 ? iou1 : iou0;
        // selected boxes via cndmask (no runtime-indexed local arrays)
        const float psx = pick1 ? P[5] : P[0];
        const float psy = pick1 ? P[6] : P[1];
        const float psw = pick1 ? P[7] : P[2];
        const float psh = pick1 ? P[8] : P[3];
        const float psc = pick1 ? P[9] : P[4];
        const float tsx = pick1 ? T[5] : T[0];
        const float tsy = pick1 ? T[6] : T[1];
        const float tsw = pick1 ? T[7] : T[2];
        const float tsh = pick1 ? T[8] : T[3];

        const float dx = psx - tsx, dy = psy - tsy;
        const float dw = sqrtf(psw) - sqrtf(tsw);
        const float dh = sqrtf(psh) - sqrtf(tsh);
        const float reg = dx * dx + dy * dy + dw * dw + dh * dh;
        const float dconf = psc - iou_best;
        loss = cls + L_COORD * reg + dconf * dconf;
    } else {
        const float d4 = P[4] - T[4];
        const float d9 = P[9] - T[9];
        loss = L_NOOBJ * (d4 * d4 + d9 * d9);
    }

    // ---- wave (64-lane) shuffle reduction ----
#pragma unroll
    for (int off = 32; off > 0; off >>= 1)
        loss += __shfl_down(loss, off, 64);

    __shared__ float wsum[BLOCK / 64];
    const int lane = threadIdx.x & 63;
    const int wave = threadIdx.x >> 6;
    if (lane == 0) wsum[wave] = loss;
    __syncthreads();
    if (threadIdx.x == 0)
        partial[blockIdx.x] = wsum[0] + wsum[1] + wsum[2] + wsum[3];
}

__global__ __launch_bounds__(BLOCK) void yolo_final(
    const float* __restrict__ partial, float* __restrict__ out) {
    float s = 0.0f;
    for (int i = threadIdx.x; i < NBLOCKS; i += BLOCK) s += partial[i];
#pragma unroll
    for (int off = 32; off > 0; off >>= 1)
        s += __shfl_down(s, off, 64);
    __shared__ float wsum[BLOCK / 64];
    const int lane = threadIdx.x & 63;
    const int wave = threadIdx.x >> 6;
    if (lane == 0) wsum[wave] = s;
    __syncthreads();
    if (threadIdx.x == 0)
        out[0] = (wsum[0] + wsum[1] + wsum[2] + wsum[3]) * (1.0f / (float)BATCH);
}

extern "C" void kernel_launch(void* const* d_in, const int* in_sizes, int n_in,
                              void* d_out, int out_size, void* d_ws, size_t ws_size,
                              hipStream_t stream) {
    const float* pred = (const float*)d_in[0];
    const float* targ = (const float*)d_in[1];
    float* out = (float*)d_out;
    float* partial = (float*)d_ws;   // NBLOCKS floats = 12.5 KB scratch

    yolo_partial<<<NBLOCKS, BLOCK, 0, stream>>>(pred, targ, partial);
    yolo_final<<<1, BLOCK, 0, stream>>>(partial, out);
}

// Round 2
// 202.827 us; speedup vs baseline: 1.0488x; 1.0488x over previous
//
#include <hip/hip_runtime.h>

#define SDIM 14
#define L_COORD 5.0f
#define L_NOOBJ 0.5f
#define BATCH 4096
#define CELLS (BATCH * SDIM * SDIM)   // 802816
#define BLOCK 256
#define NBLOCKS (CELLS / BLOCK)       // 3136
#define CELL_F 30
#define BLK_F (BLOCK * CELL_F)        // 7680 floats per tensor per block
#define BLK_F4 (BLK_F / 4)            // 1920 float4 per tensor per block

__global__ __launch_bounds__(BLOCK) void yolo_partial(
    const float* __restrict__ pred, const float* __restrict__ targ,
    float* __restrict__ partial) {
    // 60 KB LDS: [0, BLK_F) = pred cells, [BLK_F, 2*BLK_F) = targ cells
    __shared__ float s[2 * BLK_F];

    // ---- coalesced staging: 15 x float4 per thread, 1024 B/wave-instr ----
    const size_t base = (size_t)blockIdx.x * BLK_F;
    const float4* pP = reinterpret_cast<const float4*>(pred + base);
    const float4* pT = reinterpret_cast<const float4*>(targ + base);
    float4* s4 = reinterpret_cast<float4*>(s);
#pragma unroll
    for (int j = 0; j < 15; ++j) {
        const int idx = threadIdx.x + j * BLOCK;  // 0..3839
        const float4* src = (idx < BLK_F4) ? (pP + idx) : (pT + (idx - BLK_F4));
        s4[idx] = *src;
    }
    __syncthreads();

    // ---- per-cell compute from LDS ----
    const float* Pc = s + threadIdx.x * CELL_F;
    const float* Tc = s + BLK_F + threadIdx.x * CELL_F;

    float loss;
    if (Tc[4] > 0.0f) {
        // class loss (channels 10..29)
        float cls = 0.0f;
#pragma unroll
        for (int c = 10; c < 30; ++c) { float d = Pc[c] - Tc[c]; cls += d * d; }

        const float invS = 1.0f / (float)SDIM;
        const float t1x = Tc[0] * invS - Tc[2] * 0.5f;
        const float t1y = Tc[1] * invS - Tc[3] * 0.5f;
        const float t2x = Tc[0] * invS + Tc[2] * 0.5f;
        const float t2y = Tc[1] * invS + Tc[3] * 0.5f;
        const float area_t = (t2x - t1x) * (t2y - t1y);

        float iou0 = 0.0f, iou1 = 0.0f;
#pragma unroll
        for (int k = 0; k < 2; ++k) {
            const float bx = Pc[5 * k + 0], by = Pc[5 * k + 1];
            const float bw = Pc[5 * k + 2], bh = Pc[5 * k + 3];
            const float p1x = bx * invS - bw * 0.5f;
            const float p1y = by * invS - bh * 0.5f;
            const float p2x = bx * invS + bw * 0.5f;
            const float p2y = by * invS + bh * 0.5f;
            const float ltx = fmaxf(p1x, t1x), lty = fmaxf(p1y, t1y);
            const float rbx = fminf(p2x, t2x), rby = fminf(p2y, t2y);
            const float wx = fmaxf(rbx - ltx, 0.0f);
            const float wy = fmaxf(rby - lty, 0.0f);
            const float inter = wx * wy;
            const float area_p = (p2x - p1x) * (p2y - p1y);
            const float v = inter / (area_p + area_t - inter);
            if (k == 0) iou0 = v; else iou1 = v;
        }

        const bool pick1 = (iou0 <= iou1);
        const float iou_best = pick1 ? iou1 : iou0;
        const float psx = pick1 ? Pc[5] : Pc[0];
        const float psy = pick1 ? Pc[6] : Pc[1];
        const float psw = pick1 ? Pc[7] : Pc[2];
        const float psh = pick1 ? Pc[8] : Pc[3];
        const float psc = pick1 ? Pc[9] : Pc[4];
        const float tsx = pick1 ? Tc[5] : Tc[0];
        const float tsy = pick1 ? Tc[6] : Tc[1];
        const float tsw = pick1 ? Tc[7] : Tc[2];
        const float tsh = pick1 ? Tc[8] : Tc[3];

        const float dx = psx - tsx, dy = psy - tsy;
        const float dw = sqrtf(psw) - sqrtf(tsw);
        const float dh = sqrtf(psh) - sqrtf(tsh);
        const float reg = dx * dx + dy * dy + dw * dw + dh * dh;
        const float dconf = psc - iou_best;
        loss = cls + L_COORD * reg + dconf * dconf;
    } else {
        const float d4 = Pc[4] - Tc[4];
        const float d9 = Pc[9] - Tc[9];
        loss = L_NOOBJ * (d4 * d4 + d9 * d9);
    }

    // ---- wave (64-lane) shuffle reduction ----
#pragma unroll
    for (int off = 32; off > 0; off >>= 1)
        loss += __shfl_down(loss, off, 64);

    __shared__ float wsum[BLOCK / 64];
    const int lane = threadIdx.x & 63;
    const int wave = threadIdx.x >> 6;
    if (lane == 0) wsum[wave] = loss;
    __syncthreads();
    if (threadIdx.x == 0)
        partial[blockIdx.x] = wsum[0] + wsum[1] + wsum[2] + wsum[3];
}

__global__ __launch_bounds__(BLOCK) void yolo_final(
    const float* __restrict__ partial, float* __restrict__ out) {
    float s = 0.0f;
    for (int i = threadIdx.x; i < NBLOCKS; i += BLOCK) s += partial[i];
#pragma unroll
    for (int off = 32; off > 0; off >>= 1)
        s += __shfl_down(s, off, 64);
    __shared__ float wsum[BLOCK / 64];
    const int lane = threadIdx.x & 63;
    const int wave = threadIdx.x >> 6;
    if (lane == 0) wsum[wave] = s;
    __syncthreads();
    if (threadIdx.x == 0)
        out[0] = (wsum[0] + wsum[1] + wsum[2] + wsum[3]) * (1.0f / (float)BATCH);
}

extern "C" void kernel_launch(void* const* d_in, const int* in_sizes, int n_in,
                              void* d_out, int out_size, void* d_ws, size_t ws_size,
                              hipStream_t stream) {
    const float* pred = (const float*)d_in[0];
    const float* targ = (const float*)d_in[1];
    float* out = (float*)d_out;
    float* partial = (float*)d_ws;   // NBLOCKS floats = 12.5 KB scratch

    yolo_partial<<<NBLOCKS, BLOCK, 0, stream>>>(pred, targ, partial);
    yolo_final<<<1, BLOCK, 0, stream>>>(partial, out);
}